// Round 19
// baseline (447.674 us; speedup 1.0000x reference)
//
#include <hip/hip_runtime.h>
#include <hip/hip_bf16.h>
#include <cmath>

// Problem constants
#define BATCH   4096
#define NUNITS  1024
#define INSIZE  512
#define SIGSZ   6
#define KSIG    (NUNITS * SIGSZ)          // 6144
#define SAVED   (KSIG + NUNITS)           // 7168
#define KTOT    (INSIZE + KSIG + NUNITS)  // 7680
#define OUTW    (NUNITS * (SIGSZ + 1))    // 7168
#define NKT     (KTOT / 64)               // 120

// Workspace layout (ushort elements)
#define WS_AX 0LL
#define WS_AS 2097152LL
#define WS_AT 27262976LL
#define WS_BW 31457280LL
#define WS_BU 31981568LL
#define WS_ELEMS 39321600LL
#define WS_BYTES (WS_ELEMS * 2LL)         // 78,643,200
#define NPREP 256                          // flag target: every block releases once
#define SPIN_MAX (1LL << 16)               // ~27ms bounded spin, then self-convert

typedef __attribute__((ext_vector_type(8))) short bf16x8;
typedef __attribute__((ext_vector_type(8))) unsigned short u16x8;
typedef __attribute__((ext_vector_type(4))) float f32x4;
typedef __attribute__((ext_vector_type(2))) float f32x2;

__device__ __forceinline__ unsigned short f2bf(float f) {
    union { float f; unsigned int u; } c; c.f = f;
    unsigned int u = c.u;
    return (unsigned short)((u + 0x7FFFu + ((u >> 16) & 1u)) >> 16);  // RNE
}
__device__ __forceinline__ float bf2f(unsigned short h) {
    union { unsigned int u; float f; } c; c.u = ((unsigned int)h) << 16;
    return c.f;
}

// XOR-swizzled LDS index (ushort units), 128B (64 bf16) rows.
__device__ __forceinline__ int swz(int row, int bytecol) {
    return row * 64 + (((bytecol) ^ ((row & 7) << 4)) >> 1);
}

// convert share `pb` (0..255) of K-chunk `c` (8 stripes): fp32 -> bf16 in ws.
// Idempotent (pure function of immutable inputs) -> duplicate execution safe.
__device__ __forceinline__ void cvt_share(int c, int pb, int t,
    const float* __restrict__ x, const float* __restrict__ sigs,
    const float* __restrict__ states, const float* __restrict__ Ww,
    const float* __restrict__ Uw, unsigned short* __restrict__ wsm)
{
#pragma unroll
    for (int k8 = 0; k8 < 8; ++k8) {
        const int kt = c * 8 + k8;
        if (t < 512) {                       // A: 512 uint units per share-stripe
            const int g   = pb * 512 + t;
            const int row = g >> 5;          // 0..4095
            const int cp  = (g & 31) * 2;    // col within 64-col stripe
            const float* src; unsigned short* dst; int str, koff;
            if (kt < 8)        { src = x;      dst = wsm + WS_AX; str = INSIZE; koff = kt * 64; }
            else if (kt < 104) { src = sigs;   dst = wsm + WS_AS; str = KSIG;   koff = kt * 64 - 512; }
            else               { src = states; dst = wsm + WS_AT; str = NUNITS; koff = kt * 64 - 6656; }
            const f32x2 v = __builtin_nontemporal_load(
                (const f32x2*)(src + (size_t)row * str + koff + cp));
            *(unsigned int*)(dst + (size_t)row * str + koff + cp) =
                (unsigned int)f2bf(v[0]) | ((unsigned int)f2bf(v[1]) << 16);
        } else if (t < 640) {                // B: 128 uint units per share-stripe
            const int g2  = pb * 128 + (t - 512);
            const int row = g2 >> 5;         // 0..1023
            const int cp  = (g2 & 31) * 2;
            const float* src; unsigned short* dst; int str, koff;
            if (kt < 8) { src = Ww; dst = wsm + WS_BW; str = INSIZE; koff = kt * 64; }
            else        { src = Uw; dst = wsm + WS_BU; str = SAVED;  koff = kt * 64 - 512; }
            const f32x2 v = __builtin_nontemporal_load(
                (const f32x2*)(src + (size_t)row * str + koff + cp));
            *(unsigned int*)(dst + (size_t)row * str + koff + cp) =
                (unsigned int)f2bf(v[0]) | ((unsigned int)f2bf(v[1]) << 16);
        }
    }
}

// ---------------- standalone prepass (fallback path only) ----------------
__global__ __launch_bounds__(256)
void prepack(const float* __restrict__ x, const float* __restrict__ sigs,
             const float* __restrict__ states, const float* __restrict__ Ww,
             const float* __restrict__ Uw, unsigned short* __restrict__ ws)
{
    const long long stride = (long long)gridDim.x * blockDim.x;
    for (long long p = (long long)blockIdx.x * blockDim.x + threadIdx.x;
         p < 4915200LL; p += stride) {
        const float* src; unsigned short* dst; long long o;
        if (p < 262144LL)       { src = x;      dst = ws + WS_AX; o = p; }
        else if (p < 3407872LL) { src = sigs;   dst = ws + WS_AS; o = p - 262144LL; }
        else if (p < 3932160LL) { src = states; dst = ws + WS_AT; o = p - 3407872LL; }
        else if (p < 3997696LL) { src = Ww;     dst = ws + WS_BW; o = p - 3932160LL; }
        else                    { src = Uw;     dst = ws + WS_BU; o = p - 3997696LL; }
        const f32x4 v0 = __builtin_nontemporal_load((const f32x4*)(src + o * 8));
        const f32x4 v1 = __builtin_nontemporal_load((const f32x4*)(src + o * 8) + 1);
        u16x8 h;
        h[0] = f2bf(v0[0]); h[1] = f2bf(v0[1]); h[2] = f2bf(v0[2]); h[3] = f2bf(v0[3]);
        h[4] = f2bf(v1[0]); h[5] = f2bf(v1[1]); h[6] = f2bf(v1[2]); h[7] = f2bf(v1[3]);
        *(u16x8*)(dst + o * 8) = h;
    }
}

// ---------------- fused streaming GEMM + sigjoin ----------------
// Grid 256 (1 block/CU). Every block is producer AND consumer:
// converts its 1/256 share of chunk kt/8+2 at kt%8==0, releases device-scope
// flag; gates on flags[m]==256 before staging chunk m (kt%8==6 boundaries).
// Release (kt=8(m-2)) precedes poll (kt=8m-2) in every block -> progress.
// Safety valve: bounded spin, then block converts the whole chunk itself
// (idempotent) -> no hang possible even without full co-residency.
#define GLD_LDS(G, L) __builtin_amdgcn_global_load_lds(                        \
        (const __attribute__((address_space(1))) unsigned int*)(G),           \
        (__attribute__((address_space(3))) unsigned int*)(L), 16, 0, 0)

__global__ __launch_bounds__(1024, 1)
void rsig_fused(const unsigned short* __restrict__ ws,
                const float* __restrict__ Wb,
                const float* __restrict__ Ub,
                const float* __restrict__ lt,
                float* __restrict__ out,
                const float* __restrict__ x,
                const float* __restrict__ sigs,
                const float* __restrict__ states,
                const float* __restrict__ Ww,
                const float* __restrict__ Uw,
                int* __restrict__ flags,
                const int gated)
{
    __shared__ unsigned short lds[3 * 16384 + 16384];   // 96 KB ring + 32 KB stash
    __shared__ int gateStat;

    const int t   = threadIdx.x;
    const int bid = blockIdx.x;
    const int bn  = bid & 7;    // natural round-robin: same bn -> same XCD
    const int bm  = bid >> 3;   // 0..31

    const int lane = t & 63;
    const int w    = t >> 6;        // 0..15
    const int wm   = w >> 3;        // M half (0..1)
    const int wn   = (w >> 1) & 3;  // N quarter (0..3)
    const int wk   = w & 1;         // K slot
    const int lr   = lane & 15;
    const int lg   = lane >> 4;

    const unsigned short* wsAx = ws + WS_AX;
    const unsigned short* wsAs = ws + WS_AS;
    const unsigned short* wsAt = ws + WS_AT;
    const unsigned short* wsBw = ws + WS_BW;
    const unsigned short* wsBu = ws + WS_BU;
    unsigned short* wsm = (unsigned short*)ws;

    unsigned short* stash = &lds[3 * 16384];
    const int kt0 = 104 + bn * 2;   // A-tiles holding this block's states slice

    const int sRow = lane >> 3;
    const int sCol = 8 * ((lane & 7) ^ sRow);   // pre-swizzled source col (elems)

    f32x4 acc[4][2];
#pragma unroll
    for (int m = 0; m < 4; ++m)
#pragma unroll
        for (int n = 0; n < 2; ++n)
            acc[m][n] = (f32x4)0.f;

    // stage one (A,B) group pair G of tile KT into ring BUF
#define STAGE1(BUF, KT, G)                                                              \
    {                                                                                   \
        const int kt_ = (KT);                                                           \
        const unsigned short* abase; int astr, koff;                                    \
        if (kt_ < 8)        { abase = wsAx; astr = INSIZE; koff = kt_ * 64; }           \
        else if (kt_ < 104) { abase = wsAs; astr = KSIG;   koff = kt_ * 64 - 512; }     \
        else                { abase = wsAt; astr = NUNITS; koff = kt_ * 64 - 6656; }    \
        const unsigned short* bbase; int bstr, koffb;                                   \
        if (kt_ < 8)        { bbase = wsBw; bstr = INSIZE; koffb = kt_ * 64; }          \
        else                { bbase = wsBu; bstr = SAVED;  koffb = kt_ * 64 - 512; }    \
        unsigned short* base = &lds[(BUF) * 16384];                                     \
        const unsigned short* ga = abase                                                \
            + (size_t)(bm * 128 + (G) * 8 + sRow) * astr + koff + sCol;                 \
        GLD_LDS(ga, base + (G) * 512);                                                  \
        const unsigned short* gb = bbase                                                \
            + (size_t)(bn * 128 + (G) * 8 + sRow) * bstr + koffb + sCol;                \
        GLD_LDS(gb, base + 8192 + (G) * 512);                                           \
    }
    // wave role split: waves 0..13 stage group w; wave 14 stages 14+15; wave 15 polls
#define STAGE(BUF, KT)                                                                  \
    {                                                                                   \
        if (w < 14)       { STAGE1(BUF, KT, w); }                                       \
        else if (w == 14) { STAGE1(BUF, KT, 14); STAGE1(BUF, KT, 15); }                 \
    }
    // gate on chunk M; bounded spin then idempotent self-convert (no hang possible)
#define GATE(M)                                                                         \
    {                                                                                   \
        if (w == 15 && lane == 0) {                                                     \
            int ok = 0;                                                                 \
            for (long long it_ = 0; it_ < SPIN_MAX; ++it_) {                            \
                if (__hip_atomic_load(&flags[M], __ATOMIC_ACQUIRE,                      \
                                      __HIP_MEMORY_SCOPE_AGENT) >= NPREP) { ok = 1; break; } \
                __builtin_amdgcn_s_sleep(8);                                            \
            }                                                                           \
            gateStat = ok;                                                              \
        }                                                                               \
        __syncthreads();                                                                \
        if (!gateStat) {                                                                \
            for (int p_ = 0; p_ < NPREP; ++p_)                                          \
                cvt_share((M), p_, t, x, sigs, states, Ww, Uw, wsm);                    \
            __syncthreads();                                                            \
        }                                                                               \
    }

    // ---- Prologue: convert shares of chunks 0,1; release; gate chunk 0 ----
    if (gated) {
        cvt_share(0, bid, t, x, sigs, states, Ww, Uw, wsm);
        cvt_share(1, bid, t, x, sigs, states, Ww, Uw, wsm);
        __syncthreads();
        if (t == 0) {
            __threadfence();
            __hip_atomic_fetch_add(&flags[0], 1, __ATOMIC_RELEASE, __HIP_MEMORY_SCOPE_AGENT);
            __hip_atomic_fetch_add(&flags[1], 1, __ATOMIC_RELEASE, __HIP_MEMORY_SCOPE_AGENT);
        }
        GATE(0);
    }
    STAGE(0, 0);
    STAGE(1, 1);

    int cur = 0;
    for (int kt = 0; kt < NKT; ++kt) {
        const int st = kt + 2;
        if (gated && st < NKT && (st & 7) == 0) GATE(st >> 3);

        if (kt < NKT - 1) {
            if (w < 14)       { asm volatile("s_waitcnt vmcnt(2)" ::: "memory"); }
            else if (w == 14) { asm volatile("s_waitcnt vmcnt(4)" ::: "memory"); }
        } else {
            asm volatile("s_waitcnt vmcnt(0)" ::: "memory");
        }
        __builtin_amdgcn_s_barrier();
        __builtin_amdgcn_sched_barrier(0);

        // produce share of chunk kt/8+2 (consumed 16 iterations later)
        if (gated && (kt & 7) == 0 && (kt >> 3) + 2 <= 14) {
            const int cc = (kt >> 3) + 2;
            cvt_share(cc, bid, t, x, sigs, states, Ww, Uw, wsm);
            __syncthreads();   // drains stores (vmcnt0) block-wide
            if (t == 0) {
                __threadfence();   // L2 writeback -> device visibility
                __hip_atomic_fetch_add(&flags[cc], 1, __ATOMIC_RELEASE, __HIP_MEMORY_SCOPE_AGENT);
            }
        }

        if (st < NKT) {
            int nb = cur + 2; if (nb >= 3) nb -= 3;
            STAGE(nb, st);   // overwrites buf[(kt-1)%3]: readers done pre-barrier
        }

        // states stash: this tile's A half IS our epilogue states slice
        if (kt == kt0) {
            const u16x8 v = *(const u16x8*)&lds[cur * 16384 + t * 8];
            *(u16x8*)&stash[t * 8] = v;
        } else if (kt == kt0 + 1) {
            const u16x8 v = *(const u16x8*)&lds[cur * 16384 + t * 8];
            *(u16x8*)&stash[8192 + t * 8] = v;
        }

        {
            const unsigned short* aT = &lds[cur * 16384];
            const unsigned short* bT = aT + 8192;
            bf16x8 af[4], bfr[2];
#pragma unroll
            for (int m = 0; m < 4; ++m)
                af[m] = *(const bf16x8*)&aT[swz(wm * 64 + m * 16 + lr, wk * 64 + lg * 16)];
#pragma unroll
            for (int n = 0; n < 2; ++n)
                bfr[n] = *(const bf16x8*)&bT[swz(wn * 32 + n * 16 + lr, wk * 64 + lg * 16)];
#pragma unroll
            for (int m = 0; m < 4; ++m)
#pragma unroll
                for (int n = 0; n < 2; ++n)
                    acc[m][n] = __builtin_amdgcn_mfma_f32_16x16x32_bf16(af[m], bfr[n], acc[m][n], 0, 0, 0);
        }

        cur = (cur == 2) ? 0 : cur + 1;
    }

    __syncthreads();

    // ---- Phase 1: raw(+bias) -> padded LDS tile; K-split merged in-place ----
    float* rawt = (float*)lds;            // 128 rows x 132 floats (67.6 KB)
    if (wk == 0) {
#pragma unroll
        for (int n = 0; n < 2; ++n) {
            const int cc = wn * 32 + n * 16 + lr;
            const int ug = bn * 128 + cc;
            const float bias = Wb[ug] + Ub[ug];
#pragma unroll
            for (int m = 0; m < 4; ++m) {
                const int rr = wm * 64 + m * 16 + lg * 4;
#pragma unroll
                for (int i = 0; i < 4; ++i)
                    rawt[(rr + i) * 132 + cc] = acc[m][n][i] + bias;
            }
        }
    }
    __syncthreads();
    if (wk == 1) {
#pragma unroll
        for (int n = 0; n < 2; ++n) {
            const int cc = wn * 32 + n * 16 + lr;
#pragma unroll
            for (int m = 0; m < 4; ++m) {
                const int rr = wm * 64 + m * 16 + lg * 4;
#pragma unroll
                for (int i = 0; i < 4; ++i)
                    rawt[(rr + i) * 132 + cc] += acc[m][n][i];
            }
        }
    }
    __syncthreads();

    // ---- Phase 2: dense float4 store pass ----
    const float tl = expf(lt[0]);
    const int r0 = t >> 8;      // 0..3
    const int c  = t & 255;

#define PS(R, CC) bf2f(stash[((CC) >> 6) * 8192 + ((R) >> 3) * 512 + ((R) & 7) * 64 \
                            + (((((CC) & 63) >> 3) ^ ((R) & 7)) << 3) + ((CC) & 7)])

    for (int pass = 0; pass < 32; ++pass) {
        const int r = pass * 4 + r0;
        const long long b = (long long)bm * 128 + r;
        if (c < 192) {
            const int u  = (2 * c) / 3;
            const int cs = c % 3;
            const unsigned short* srow = wsAs + b * KSIG + bn * 768;
            const ushort4 sin = *(const ushort4*)(srow + c * 4);
            const float e0 = bf2f(sin.x), e1 = bf2f(sin.y);
            const float e2 = bf2f(sin.z), e3 = bf2f(sin.w);
            float4 o;
            if (cs == 0) {
                const float d = rawt[r * 132 + u] - PS(r, u);
                o.x = e0 + d;
                o.y = e1 + tl;
                o.z = e2 + d  * (0.5f * d  + e0);
                o.w = e3 + tl * (0.5f * d  + e0);
            } else if (cs == 1) {
                const float d  = rawt[r * 132 + u]     - PS(r, u);
                const float dn = rawt[r * 132 + u + 1] - PS(r, u + 1);
                const float s1 = bf2f(srow[u * 6 + 1]);
                o.x = e0 + d  * (0.5f * tl + s1);
                o.y = e1 + tl * (0.5f * tl + s1);
                o.z = e2 + dn;
                o.w = e3 + tl;
            } else {
                const float d = rawt[r * 132 + u] - PS(r, u);
                const unsigned int sv = *(const unsigned int*)(srow + u * 6);
                const float s0 = bf2f((unsigned short)(sv & 0xffffu));
                const float s1 = bf2f((unsigned short)(sv >> 16));
                o.x = e0 + d  * (0.5f * d  + s0);
                o.y = e1 + tl * (0.5f * d  + s0);
                o.z = e2 + d  * (0.5f * tl + s1);
                o.w = e3 + tl * (0.5f * tl + s1);
            }
            *(float4*)(out + b * OUTW + bn * 768 + c * 4) = o;
        } else if (c < 224) {
            const int cc = (c - 192) * 4;
            const float4 rv = *(const float4*)&rawt[r * 132 + cc];
            *(float4*)(out + b * OUTW + KSIG + bn * 128 + cc) = rv;
        }
    }
#undef PS
#undef STAGE
#undef STAGE1
#undef GATE
}

extern "C" void kernel_launch(void* const* d_in, const int* in_sizes, int n_in,
                              void* d_out, int out_size, void* d_ws, size_t ws_size,
                              hipStream_t stream) {
    const float* x      = (const float*)d_in[0];
    const float* sigs   = (const float*)d_in[1];
    const float* states = (const float*)d_in[2];
    const float* Ww     = (const float*)d_in[3];
    const float* Wb     = (const float*)d_in[4];
    const float* Uw     = (const float*)d_in[5];
    const float* Ub     = (const float*)d_in[6];
    const float* lt     = (const float*)d_in[7];
    float* out = (float*)d_out;

    unsigned short* ws = (unsigned short*)d_ws;
    int* flags = (int*)((char*)d_ws + WS_BYTES);
    const bool fits = ws_size >= (size_t)WS_BYTES + 64;

    if (fits) {
        hipMemsetAsync(flags, 0, 64, stream);
        hipLaunchKernelGGL(rsig_fused, dim3(256), dim3(1024), 0, stream,
                           ws, Wb, Ub, lt, out, x, sigs, states, Ww, Uw, flags, 1);
    } else {
        hipLaunchKernelGGL(prepack, dim3(2048), dim3(256), 0, stream,
                           x, sigs, states, Ww, Uw, ws);
        hipLaunchKernelGGL(rsig_fused, dim3(256), dim3(1024), 0, stream,
                           ws, Wb, Ub, lt, out, x, sigs, states, Ww, Uw, (int*)d_ws, 0);
    }
}